// Round 1
// baseline (1316.520 us; speedup 1.0000x reference)
//
#include <hip/hip_runtime.h>
#include <math.h>

// N=100000 nodes, D=128 feats, E=1600000 edges.
// f = alpha*(Ax - x) + beta*(-(x-1)*x) + clip(src*x0,-1,1)*0.1,  Ax[row] += w*x[col]
//
// R4: bucket-CSR redesign. Rows grouped into buckets of 32; edges only need
// bucket-level grouping (not per-row sorting) because gather accumulates the
// bucket's 32 rows in an LDS tile with ds_add_f32.
//  - count: per-block LDS histogram (3125 buckets), ~600K no-return flush atomics
//  - scan:  single-wave scan of 3125 bucket counts
//  - place: LDS-rank + one global atomic-return per (block,bucket); edge records
//           land in contiguous runs -> kills the 8x partial-line write amplification
//  - gather: block-per-bucket, LDS f32 accumulation (stride-32 lane map = bank-free),
//            fused epilogue

#define D_FEAT 128
#define RPB 32              // rows per bucket (N=100000 -> NB=3125, exact)
#define EPT 32              // edges per thread in count/place
#define EPB (256 * EPT)     // 8192 edges per block
#define NB_MAX 3136         // static LDS histogram size (>= NB)

__device__ __forceinline__ float sigmoid_f(float v) {
    return 1.0f / (1.0f + __expf(-v));
}

__global__ void zero_kernel(int* __restrict__ p, int n) {
    int i = blockIdx.x * blockDim.x + threadIdx.x;
    if (i < n) p[i] = 0;
}

// Per-block LDS histogram of bucket ids, flushed with no-return global atomics.
__global__ __launch_bounds__(256) void count_kernel(const int* __restrict__ rows,
                                                    int* __restrict__ cnt, int E, int NB) {
    __shared__ int hist[NB_MAX];
    int t = threadIdx.x;
    for (int i = t; i < NB; i += 256) hist[i] = 0;
    __syncthreads();
    int base = blockIdx.x * EPB;
#pragma unroll
    for (int k = 0; k < EPT; ++k) {
        int e = base + k * 256 + t;
        if (e < E) atomicAdd(&hist[rows[e] >> 5], 1);
    }
    __syncthreads();
    for (int i = t; i < NB; i += 256) {
        int c = hist[i];
        if (c) atomicAdd(&cnt[i], c);
    }
}

// One-wave exclusive scan of bucket counts -> bstart (for gather) and gcur
// (mutable reservation cursor for place). bstart[NB] = E.
__global__ void scan_kernel(const int* __restrict__ cnt, int* __restrict__ bstart,
                            int* __restrict__ gcur, int NB) {
    int lane = threadIdx.x;   // 64 threads
    int carry = 0;
    for (int base = 0; base < NB; base += 64) {
        int idx = base + lane;
        int v = (idx < NB) ? cnt[idx] : 0;
        int incl = v;
#pragma unroll
        for (int d = 1; d < 64; d <<= 1) {
            int tt = __shfl_up(incl, d);
            if (lane >= d) incl += tt;
        }
        int tot = __shfl(incl, 63);
        int excl = incl - v + carry;
        if (idx < NB) { bstart[idx] = excl; gcur[idx] = excl; }
        carry += tot;
    }
    if (lane == 0) bstart[NB] = carry;
}

// Block-aggregated placement: LDS rank within (block,bucket), one global
// atomic-return per (block,bucket) to reserve a contiguous range, contiguous
// packed (rl<<20|col, w*alpha) stores.
__global__ __launch_bounds__(256) void place_kernel(const int* __restrict__ rows,
                                                    const int* __restrict__ cols,
                                                    const float* __restrict__ w,
                                                    const float* __restrict__ alpha_p,
                                                    int* __restrict__ gcur,
                                                    int2* __restrict__ col_w, int E, int NB) {
    __shared__ int hist[NB_MAX];
    __shared__ int basep[NB_MAX];
    const float alpha = sigmoid_f(alpha_p[0]) * 0.1f;
    int t = threadIdx.x;
    for (int i = t; i < NB; i += 256) hist[i] = 0;
    __syncthreads();

    int base = blockIdx.x * EPB;
    int r[EPT];
#pragma unroll
    for (int k = 0; k < EPT; ++k) {
        int e = base + k * 256 + t;
        r[k] = (e < E) ? rows[e] : -1;
        if (r[k] >= 0) atomicAdd(&hist[r[k] >> 5], 1);
    }
    __syncthreads();

    for (int i = t; i < NB; i += 256) {
        int c = hist[i];
        basep[i] = atomicAdd(&gcur[i], c);   // unconditional: pipelines better
        hist[i] = 0;                          // reset for rank phase
    }
    __syncthreads();

#pragma unroll
    for (int k = 0; k < EPT; ++k) {
        if (r[k] < 0) continue;
        int e = base + k * 256 + t;
        int bkt = r[k] >> 5;
        int rl  = r[k] & 31;
        int rank = atomicAdd(&hist[bkt], 1);
        int pos = basep[bkt] + rank;
        col_w[pos] = make_int2((rl << 20) | cols[e], __float_as_int(w[e] * alpha));
    }
}

// Block-per-bucket gather. acc[32][128] f32 in LDS; half-wave per edge; lane fl
// handles feats {fl, fl+32, fl+64, fl+96} so ds_add_f32 is bank-conflict-free.
__global__ __launch_bounds__(256) void gather_kernel(const float* __restrict__ x,
                                                     const float* __restrict__ x0,
                                                     const int* __restrict__ bstart,
                                                     const int2* __restrict__ col_w,
                                                     const float* __restrict__ alpha_p,
                                                     const float* __restrict__ beta_p,
                                                     const float* __restrict__ src_p,
                                                     float* __restrict__ out, int N) {
    __shared__ float acc[RPB * D_FEAT];   // 16 KiB
    const float alpha = sigmoid_f(alpha_p[0]) * 0.1f;
    const float beta  = sigmoid_f(beta_p[0]) * 0.1f;
    const float src   = src_p[0];

    int b = blockIdx.x;
    int t = threadIdx.x;
    for (int i = t; i < RPB * D_FEAT; i += 256) acc[i] = 0.0f;
    __syncthreads();

    int start = bstart[b];
    int end   = bstart[b + 1];
    int h  = t >> 5;      // 8 half-waves per block
    int fl = t & 31;

    int j = start + h;
    for (; j + 8 < end; j += 16) {        // unroll 2: edges j and j+8
        int2 r0 = col_w[j];
        int2 r1 = col_w[j + 8];
        int   c0 = r0.x & 0xFFFFF,  c1 = r1.x & 0xFFFFF;
        int   a0 = (r0.x >> 20) * D_FEAT + fl;
        int   a1 = (r1.x >> 20) * D_FEAT + fl;
        float w0 = __int_as_float(r0.y), w1 = __int_as_float(r1.y);
        const float* p0 = x + c0 * D_FEAT + fl;
        const float* p1 = x + c1 * D_FEAT + fl;
        float v00 = p0[0], v01 = p0[32], v02 = p0[64], v03 = p0[96];
        float v10 = p1[0], v11 = p1[32], v12 = p1[64], v13 = p1[96];
        atomicAdd(&acc[a0],      w0 * v00);
        atomicAdd(&acc[a0 + 32], w0 * v01);
        atomicAdd(&acc[a0 + 64], w0 * v02);
        atomicAdd(&acc[a0 + 96], w0 * v03);
        atomicAdd(&acc[a1],      w1 * v10);
        atomicAdd(&acc[a1 + 32], w1 * v11);
        atomicAdd(&acc[a1 + 64], w1 * v12);
        atomicAdd(&acc[a1 + 96], w1 * v13);
    }
    if (j < end) {
        int2 r0 = col_w[j];
        int   c0 = r0.x & 0xFFFFF;
        int   a0 = (r0.x >> 20) * D_FEAT + fl;
        float w0 = __int_as_float(r0.y);
        const float* p0 = x + c0 * D_FEAT + fl;
        atomicAdd(&acc[a0],      w0 * p0[0]);
        atomicAdd(&acc[a0 + 32], w0 * p0[32]);
        atomicAdd(&acc[a0 + 64], w0 * p0[64]);
        atomicAdd(&acc[a0 + 96], w0 * p0[96]);
    }
    __syncthreads();

    // Fused epilogue: 32 rows x 32 float4 chunks = 1024 jobs, 4 per thread.
    int rbase = b * RPB;
    const float4* x4  = (const float4*)x;
    const float4* x04 = (const float4*)x0;
    float4* out4 = (float4*)out;
    for (int q = t; q < RPB * (D_FEAT / 4); q += 256) {
        int rl = q >> 5;          // 32 float4 per row
        int c4 = q & 31;
        int row = rbase + rl;
        if (row < N) {
            float4 xv = x4[row * 32 + c4];
            float4 zv = x04[row * 32 + c4];
            float4 av = *(const float4*)&acc[rl * D_FEAT + c4 * 4];
            float4 o;
            o.x = av.x - alpha * xv.x + beta * (-(xv.x - 1.0f) * xv.x)
                + fminf(fmaxf(src * zv.x, -1.0f), 1.0f) * 0.1f;
            o.y = av.y - alpha * xv.y + beta * (-(xv.y - 1.0f) * xv.y)
                + fminf(fmaxf(src * zv.y, -1.0f), 1.0f) * 0.1f;
            o.z = av.z - alpha * xv.z + beta * (-(xv.z - 1.0f) * xv.z)
                + fminf(fmaxf(src * zv.z, -1.0f), 1.0f) * 0.1f;
            o.w = av.w - alpha * xv.w + beta * (-(xv.w - 1.0f) * xv.w)
                + fminf(fmaxf(src * zv.w, -1.0f), 1.0f) * 0.1f;
            out4[row * 32 + c4] = o;
        }
    }
}

extern "C" void kernel_launch(void* const* d_in, const int* in_sizes, int n_in,
                              void* d_out, int out_size, void* d_ws, size_t ws_size,
                              hipStream_t stream) {
    const float* x   = (const float*)d_in[1];
    const int*   ei  = (const int*)d_in[2];
    const float* ew  = (const float*)d_in[3];
    const float* x0  = (const float*)d_in[4];
    const float* alp = (const float*)d_in[5];
    const float* bet = (const float*)d_in[6];
    const float* src = (const float*)d_in[7];
    float* out = (float*)d_out;

    const int E = in_sizes[3];
    const int N = out_size / D_FEAT;
    const int* rows = ei;
    const int* cols = ei + E;

    const int NB = (N + RPB - 1) / RPB;        // 3125 (<= NB_MAX)
    const int nEdgeBlk = (E + EPB - 1) / EPB;  // 196

    char* ws = (char*)d_ws;
    int* cnt    = (int*)ws;  ws += ((size_t)NB * 4 + 15) & ~15ull;
    int* bstart = (int*)ws;  ws += ((size_t)(NB + 1) * 4 + 15) & ~15ull;
    int* gcur   = (int*)ws;  ws += ((size_t)NB * 4 + 15) & ~15ull;
    int2* col_w = (int2*)ws; ws += ((size_t)E * 8 + 15) & ~15ull;

    zero_kernel<<<(NB + 255) / 256, 256, 0, stream>>>(cnt, NB);
    count_kernel<<<nEdgeBlk, 256, 0, stream>>>(rows, cnt, E, NB);
    scan_kernel<<<1, 64, 0, stream>>>(cnt, bstart, gcur, NB);
    place_kernel<<<nEdgeBlk, 256, 0, stream>>>(rows, cols, ew, alp, gcur, col_w, E, NB);
    gather_kernel<<<NB, 256, 0, stream>>>(x, x0, bstart, col_w, alp, bet, src, out, N);
}

// Round 2
// 332.248 us; speedup vs baseline: 3.9625x; 3.9625x over previous
//
#include <hip/hip_runtime.h>
#include <math.h>

// N=100000 nodes, D=128 feats, E=1600000 edges.
// f = alpha*(Ax - x) + beta*(-(x-1)*x) + clip(src*x0,-1,1)*0.1,  Ax[row] += w*x[col]
//
// R5: proven R3 gather (1 wave/row, float4) + cheap bucket build.
//  - count: per-block LDS histogram over 391 buckets (rows>>8), no-return flushes
//  - scan:  one-wave scan of bucket counts -> bstart/gcur
//  - place: LDS rank + 1 atomic-return per (block,bucket); raw (rl<<17|col, w*a)
//           records land in ~21-record contiguous runs (kills 8x write amp).
//           Raw buffer = d_out reused as scratch (dead until gather).
//  - sort:  block-per-bucket LDS counting sort by row; writes sorted records +
//           per-row end offsets (off[r] = end, start = off[r-1]).
//  - gather: R3's kernel verbatim (measured 135us @ 3.6TB/s).

#define D_FEAT 128
#define RPB 256             // rows per bucket -> NB = 391
#define NB_MAX 400
#define SORT_CAP 5120       // LDS-staged records per bucket (mean 4092, sd ~64)
#define EPB 8192            // edges per block in count/place (256 thr x 32)

__device__ __forceinline__ float sigmoid_f(float v) {
    return 1.0f / (1.0f + __expf(-v));
}

__global__ void zero_kernel(int* __restrict__ p, int n) {
    int i = blockIdx.x * blockDim.x + threadIdx.x;
    if (i < n) p[i] = 0;
}

// Per-block LDS histogram of bucket ids (row>>8), flushed with no-return atomics.
__global__ __launch_bounds__(256) void count_kernel(const int* __restrict__ rows,
                                                    int* __restrict__ cnt, int E, int NB) {
    __shared__ int hist[NB_MAX];
    int t = threadIdx.x;
    for (int i = t; i < NB; i += 256) hist[i] = 0;
    __syncthreads();
    int nE4 = E >> 2;
    int base4 = blockIdx.x * (EPB / 4);
#pragma unroll
    for (int k = 0; k < EPB / 4 / 256; ++k) {           // 8 int4 per thread
        int i4 = base4 + k * 256 + t;
        if (i4 < nE4) {
            int4 r = ((const int4*)rows)[i4];
            atomicAdd(&hist[r.x >> 8], 1);
            atomicAdd(&hist[r.y >> 8], 1);
            atomicAdd(&hist[r.z >> 8], 1);
            atomicAdd(&hist[r.w >> 8], 1);
        }
    }
    if (blockIdx.x == 0 && t < (E & 3))                 // scalar tail
        atomicAdd(&hist[rows[(nE4 << 2) + t] >> 8], 1);
    __syncthreads();
    for (int i = t; i < NB; i += 256) {
        int c = hist[i];
        if (c) atomicAdd(&cnt[i], c);
    }
}

// One-wave exclusive scan of bucket counts -> bstart (immutable) and gcur
// (mutable reservation cursors). bstart[NB] = E.
__global__ void scan_kernel(const int* __restrict__ cnt, int* __restrict__ bstart,
                            int* __restrict__ gcur, int NB) {
    int lane = threadIdx.x;   // 64 threads
    int carry = 0;
    for (int base = 0; base < NB; base += 64) {
        int idx = base + lane;
        int v = (idx < NB) ? cnt[idx] : 0;
        int incl = v;
#pragma unroll
        for (int d = 1; d < 64; d <<= 1) {
            int tt = __shfl_up(incl, d);
            if (lane >= d) incl += tt;
        }
        int tot = __shfl(incl, 63);
        int excl = incl - v + carry;
        if (idx < NB) { bstart[idx] = excl; gcur[idx] = excl; }
        carry += tot;
    }
    if (lane == 0) bstart[NB] = carry;
}

// Bucket placement: LDS rank within (block,bucket), one atomic-return per
// (block,bucket), packed (rl<<17|col, w*alpha) records into contiguous runs.
__global__ __launch_bounds__(256) void place_kernel(const int* __restrict__ rows,
                                                    const int* __restrict__ cols,
                                                    const float* __restrict__ w,
                                                    const float* __restrict__ alpha_p,
                                                    int* __restrict__ gcur,
                                                    int2* __restrict__ raw, int E, int NB) {
    __shared__ int hist[NB_MAX];
    __shared__ int basep[NB_MAX];
    const float alpha = sigmoid_f(alpha_p[0]) * 0.1f;
    int t = threadIdx.x;
    for (int i = t; i < NB; i += 256) hist[i] = 0;
    __syncthreads();

    int base = blockIdx.x * EPB;
#pragma unroll
    for (int k = 0; k < EPB / 256; ++k) {
        int e = base + k * 256 + t;
        if (e < E) atomicAdd(&hist[rows[e] >> 8], 1);
    }
    __syncthreads();
    for (int i = t; i < NB; i += 256) {
        basep[i] = atomicAdd(&gcur[i], hist[i]);
        hist[i] = 0;
    }
    __syncthreads();
#pragma unroll
    for (int k = 0; k < EPB / 256; ++k) {
        int e = base + k * 256 + t;
        if (e >= E) continue;
        int r = rows[e];
        int bkt = r >> 8;
        int rl  = r & 255;
        int rank = atomicAdd(&hist[bkt], 1);
        raw[basep[bkt] + rank] = make_int2((rl << 17) | cols[e],
                                           __float_as_int(w[e] * alpha));
    }
}

// Block-per-bucket counting sort by row-local id. Stages the bucket run in LDS,
// builds per-row hist, scans (also emitting global per-row END offsets), then
// scatters sorted (col, w) records. Slow path (cnt > SORT_CAP): two global
// passes, no staging (correct for any size; statistically never taken here).
__global__ __launch_bounds__(256) void sort_kernel(const int2* __restrict__ raw,
                                                   int2* __restrict__ srt,
                                                   const int* __restrict__ bstart,
                                                   int* __restrict__ off, int N, int NB) {
    __shared__ int2 sbuf[SORT_CAP];     // 40 KiB
    __shared__ int hist[RPB];
    __shared__ int scanb[RPB];
    __shared__ int cursor[RPB];
    int b = blockIdx.x;
    int t = threadIdx.x;
    int bs = bstart[b], be = bstart[b + 1];
    int cntb = be - bs;
    hist[t] = 0;
    __syncthreads();

    bool fast = (cntb <= SORT_CAP);
    if (fast) {
        for (int i = t; i < cntb; i += 256) {
            int2 v = raw[bs + i];
            sbuf[i] = v;
            atomicAdd(&hist[v.x >> 17], 1);
        }
    } else {
        for (int i = t; i < cntb; i += 256)
            atomicAdd(&hist[raw[bs + i].x >> 17], 1);
    }
    __syncthreads();

    // Hillis-Steele inclusive scan over 256 counts.
    int v = hist[t];
    scanb[t] = v;
    __syncthreads();
    for (int d = 1; d < 256; d <<= 1) {
        int tv = (t >= d) ? scanb[t - d] : 0;
        __syncthreads();
        scanb[t] += tv;
        __syncthreads();
    }
    int incl = scanb[t];
    int excl = incl - v;
    int row = b * RPB + t;
    if (row < N) off[row] = bs + incl;        // END offset; start = off[row-1]
    cursor[t] = bs + excl;
    __syncthreads();

    if (fast) {
        for (int i = t; i < cntb; i += 256) {
            int2 r = sbuf[i];
            int rl = r.x >> 17;
            int pos = atomicAdd(&cursor[rl], 1);
            srt[pos] = make_int2(r.x & 0x1FFFF, r.y);
        }
    } else {
        for (int i = t; i < cntb; i += 256) {
            int2 r = raw[bs + i];
            int rl = r.x >> 17;
            int pos = atomicAdd(&cursor[rl], 1);
            srt[pos] = make_int2(r.x & 0x1FFFF, r.y);
        }
    }
}

// One 64-lane wave per row; two half-waves each unrolled x2 -> 4 x-row loads in
// flight. off[r] = end of row r; start = off[r-1] (0 for r=0).  [R3, measured]
__global__ void gather_kernel(const float* __restrict__ x,
                              const float* __restrict__ x0,
                              const int* __restrict__ off,
                              const int2* __restrict__ col_w,
                              const float* __restrict__ alpha_p,
                              const float* __restrict__ beta_p,
                              const float* __restrict__ src_p,
                              float* __restrict__ out, int N) {
    const float alpha = sigmoid_f(alpha_p[0]) * 0.1f;
    const float beta  = sigmoid_f(beta_p[0]) * 0.1f;
    const float src   = src_p[0];

    int gtid = blockIdx.x * blockDim.x + threadIdx.x;
    int row  = gtid >> 6;
    if (row >= N) return;
    int lane  = threadIdx.x & 63;
    int half  = lane >> 5;
    int flane = lane & 31;

    int start = (row == 0) ? 0 : off[row - 1];
    int end   = off[row];

    const float4* x4 = (const float4*)x;
    float4 a0 = make_float4(0.f, 0.f, 0.f, 0.f);
    float4 a1 = make_float4(0.f, 0.f, 0.f, 0.f);

    int j = start + half;
    for (; j + 2 < end; j += 4) {
        int2 cw0 = col_w[j];
        int2 cw1 = col_w[j + 2];
        float4 v0 = x4[(long long)cw0.x * 32 + flane];
        float4 v1 = x4[(long long)cw1.x * 32 + flane];
        float w0 = __int_as_float(cw0.y);
        float w1 = __int_as_float(cw1.y);
        a0.x += w0 * v0.x; a0.y += w0 * v0.y; a0.z += w0 * v0.z; a0.w += w0 * v0.w;
        a1.x += w1 * v1.x; a1.y += w1 * v1.y; a1.z += w1 * v1.z; a1.w += w1 * v1.w;
    }
    if (j < end) {
        int2 cw = col_w[j];
        float4 v = x4[(long long)cw.x * 32 + flane];
        float wv = __int_as_float(cw.y);
        a0.x += wv * v.x; a0.y += wv * v.y; a0.z += wv * v.z; a0.w += wv * v.w;
    }
    float4 acc;
    acc.x = a0.x + a1.x; acc.y = a0.y + a1.y;
    acc.z = a0.z + a1.z; acc.w = a0.w + a1.w;

    acc.x += __shfl_xor(acc.x, 32);
    acc.y += __shfl_xor(acc.y, 32);
    acc.z += __shfl_xor(acc.z, 32);
    acc.w += __shfl_xor(acc.w, 32);

    if (half == 0) {
        long long base = (long long)row * 32 + flane;
        float4 xv  = x4[base];
        float4 x0v = ((const float4*)x0)[base];
        float xs[4]  = {xv.x, xv.y, xv.z, xv.w};
        float zs[4]  = {x0v.x, x0v.y, x0v.z, x0v.w};
        float as[4]  = {acc.x, acc.y, acc.z, acc.w};
        float os[4];
#pragma unroll
        for (int k = 0; k < 4; ++k) {
            float reaction = -(xs[k] - 1.0f) * xs[k];
            float st = fminf(fmaxf(src * zs[k], -1.0f), 1.0f);
            os[k] = as[k] - alpha * xs[k] + beta * reaction + st * 0.1f;
        }
        ((float4*)out)[base] = make_float4(os[0], os[1], os[2], os[3]);
    }
}

extern "C" void kernel_launch(void* const* d_in, const int* in_sizes, int n_in,
                              void* d_out, int out_size, void* d_ws, size_t ws_size,
                              hipStream_t stream) {
    const float* x   = (const float*)d_in[1];
    const int*   ei  = (const int*)d_in[2];
    const float* ew  = (const float*)d_in[3];
    const float* x0  = (const float*)d_in[4];
    const float* alp = (const float*)d_in[5];
    const float* bet = (const float*)d_in[6];
    const float* src = (const float*)d_in[7];
    float* out = (float*)d_out;

    const int E = in_sizes[3];
    const int N = out_size / D_FEAT;
    const int* rows = ei;
    const int* cols = ei + E;

    const int NB = (N + RPB - 1) / RPB;          // 391
    const int nEdgeBlk = (E + EPB - 1) / EPB;    // 196

    char* ws = (char*)d_ws;
    int* cnt    = (int*)ws;  ws += ((size_t)NB * 4 + 15) & ~15ull;
    int* bstart = (int*)ws;  ws += ((size_t)(NB + 1) * 4 + 15) & ~15ull;
    int* gcur   = (int*)ws;  ws += ((size_t)NB * 4 + 15) & ~15ull;
    int* off    = (int*)ws;  ws += ((size_t)N * 4 + 15) & ~15ull;
    int2* col_w = (int2*)ws; ws += ((size_t)E * 8 + 15) & ~15ull;

    // Raw (unsorted) records: reuse d_out as scratch if it fits (it's dead
    // until gather's epilogue, which runs after sort consumed raw).
    int2* raw;
    if ((size_t)out_size >= (size_t)E * 8) {
        raw = (int2*)d_out;
    } else {
        raw = (int2*)ws;     ws += ((size_t)E * 8 + 15) & ~15ull;
    }

    zero_kernel<<<(NB + 255) / 256, 256, 0, stream>>>(cnt, NB);
    count_kernel<<<nEdgeBlk, 256, 0, stream>>>(rows, cnt, E, NB);
    scan_kernel<<<1, 64, 0, stream>>>(cnt, bstart, gcur, NB);
    place_kernel<<<nEdgeBlk, 256, 0, stream>>>(rows, cols, ew, alp, gcur, raw, E, NB);
    sort_kernel<<<NB, 256, 0, stream>>>(raw, col_w, bstart, off, N, NB);
    {
        long long threads = (long long)N * 64;
        int grid = (int)((threads + 255) / 256);
        gather_kernel<<<grid, 256, 0, stream>>>(x, x0, off, col_w, alp, bet, src, out, N);
    }
}